// Round 18
// baseline (507.443 us; speedup 1.0000x reference)
//
#include <hip/hip_runtime.h>
#include <math.h>

// ---------------------------------------------------------------------------
// SimpleVQAutoEncoder forward.
// k_enc: FUSED conv1(+pool+gelu[fast-erf, |err|<1e-6], split-bf16 in LDS)
//   + conv2 MFMA GEMM + pool (stride-65) + VQ (split-bf16 MFMA distances vs
//   L2-resident pre-split codebook) + near-tie flagging (eps 0.012+0.0003|b|)
//   + loss. Gelu-approx error (~1e-4 on distances) absorbed by eps guard;
//   flagged positions repaired in fp64 with EXACT erf => indices == numpy.
// Decoder: k_dec (LUT adds -> exact-erff gelu tile -> conv4 -> clip).
// Outputs d_out (fp32): recon 4194304 | indices 262144 | loss 1
// ---------------------------------------------------------------------------

#define GELUF(v) (0.5f * (v) * (1.0f + erff((v) * 0.70710678118654752440f)))
#define MAXFLAG 262144

typedef __attribute__((ext_vector_type(8))) short short8;
typedef __attribute__((ext_vector_type(4))) float float4v;

static __device__ inline unsigned short f2bf(float f) {
    unsigned u = __float_as_uint(f);
    unsigned r = (u + 0x7FFFu + ((u >> 16) & 1u)) >> 16;
    return (unsigned short)r;
}
static __device__ inline float bf2f(unsigned short h) {
    return __uint_as_float(((unsigned)h) << 16);
}

// Abramowitz-Stegun 7.1.26 erf, branch-free, |abs err| ~< 1e-6 total.
static __device__ inline float fast_erf(float x) {
    float a = fabsf(x);
    float t = __builtin_amdgcn_rcpf(fmaf(0.3275911f, a, 1.0f));
    float p = fmaf(1.061405429f, t, -1.453152027f);
    p = fmaf(p, t, 1.421413741f);
    p = fmaf(p, t, -0.284496736f);
    p = fmaf(p, t, 0.254829592f);
    p = p * t;
    float e = __expf(-a * a);
    float r = fmaf(-p, e, 1.0f);
    return copysignf(r, x);
}
#define GELUF_FAST(v) (0.5f * (v) * (1.0f + fast_erf((v) * 0.70710678118654752440f)))

// Fused encoder+VQ. Block = 16x16 conv2 positions (one 8x8 pooled tile).
__global__ __launch_bounds__(256) void k_enc(const float* __restrict__ x,
                                             const float* __restrict__ w1,
                                             const float* __restrict__ b1,
                                             const unsigned short* __restrict__ w2h,
                                             const unsigned short* __restrict__ w2l,
                                             const float* __restrict__ b2,
                                             const unsigned short* __restrict__ cbh,
                                             const unsigned short* __restrict__ cbl,
                                             const float* __restrict__ c2g,
                                             float* __restrict__ idx_out,
                                             float* __restrict__ loss_out,
                                             int* __restrict__ nflag,
                                             int* __restrict__ flags) {
    __shared__ __align__(16) float s_scratch[2112];  // x window 38x40 -> pool (stride 65)
    __shared__ __align__(16) unsigned short s_hi[18 * 2 * 18 * 8];
    __shared__ __align__(16) unsigned short s_lo[18 * 2 * 18 * 8];
    __shared__ float s_best[64], s_best2[64];
    __shared__ int   s_bi[64];

    int tid = threadIdx.x;
    int n = blockIdx.x >> 6;
    int tile = blockIdx.x & 63;
    int cx0 = (tile & 7) << 4, cy0 = (tile >> 3) << 4;

    // stage x window: 38x38, LDS stride 40, origin (2*cy0-3, 2*cx0-3)
    {
        const float* xin = x + (size_t)n * 65536;
        int gy0 = 2 * cy0 - 3, gx0 = 2 * cx0 - 3;
        for (int e = tid; e < 1444; e += 256) {
            int r = e / 38, c = e - r * 38;
            int gy = gy0 + r, gx = gx0 + c;
            float v = 0.0f;
            if (gy >= 0 && gy < 256 && gx >= 0 && gx < 256) v = xin[gy * 256 + gx];
            s_scratch[r * 40 + c] = v;
        }
    }
    __syncthreads();

    // conv1 phase: 18x18 halo pixels x 16ch, fast-erf gelu, packed b128 writes.
    for (int e = tid; e < 324; e += 256) {
        int r = e / 18, c = e - r * 18;
        int hy = cy0 - 1 + r, hx = cx0 - 1 + c;
        uint ph[8], pl[8];
        if (hy >= 0 && hy < 128 && hx >= 0 && hx < 128) {
            float patch[4][4];
            const float* sp = s_scratch + (2 * r) * 40 + 2 * c;
#pragma unroll
            for (int i = 0; i < 4; i++)
#pragma unroll
                for (int j = 0; j < 4; j++)
                    patch[i][j] = sp[i * 40 + j];
            unsigned short hi[16], lo[16];
#pragma unroll
            for (int ch = 0; ch < 16; ch++) {
                float m = -INFINITY;
#pragma unroll
                for (int sy = 0; sy < 2; sy++)
#pragma unroll
                    for (int sx = 0; sx < 2; sx++) {
                        float acc = b1[ch];
#pragma unroll
                        for (int ky = 0; ky < 3; ky++)
#pragma unroll
                            for (int kx = 0; kx < 3; kx++)
                                acc += w1[ch * 9 + ky * 3 + kx] * patch[sy + ky][sx + kx];
                        m = fmaxf(m, acc);
                    }
                float g = GELUF_FAST(m);
                hi[ch] = f2bf(g);
                lo[ch] = f2bf(g - bf2f(hi[ch]));
            }
#pragma unroll
            for (int dw = 0; dw < 8; dw++) {
                ph[dw] = (uint)hi[2 * dw] | ((uint)hi[2 * dw + 1] << 16);
                pl[dw] = (uint)lo[2 * dw] | ((uint)lo[2 * dw + 1] << 16);
            }
        } else {
#pragma unroll
            for (int dw = 0; dw < 8; dw++) { ph[dw] = 0; pl[dw] = 0; }
        }
        ((uint4*)s_hi)[(r * 2) * 18 + c]     = make_uint4(ph[0], ph[1], ph[2], ph[3]);
        ((uint4*)s_hi)[(r * 2 + 1) * 18 + c] = make_uint4(ph[4], ph[5], ph[6], ph[7]);
        ((uint4*)s_lo)[(r * 2) * 18 + c]     = make_uint4(pl[0], pl[1], pl[2], pl[3]);
        ((uint4*)s_lo)[(r * 2 + 1) * 18 + c] = make_uint4(pl[4], pl[5], pl[6], pl[7]);
    }
    __syncthreads();

    // conv2 MFMA phase; B-frags from global (L2-hot w2h/w2l).
    int lane = tid & 63, wid = tid >> 6;
    int m = lane & 15, quad = lane >> 4;
    int tl = quad >> 1, half = quad & 1;

    float4v acc[4][2];
#pragma unroll
    for (int mt = 0; mt < 4; mt++)
#pragma unroll
        for (int nt = 0; nt < 2; nt++)
            acc[mt][nt] = (float4v){0.0f, 0.0f, 0.0f, 0.0f};

    for (int s = 0; s < 5; s++) {
        int tA = (s < 4) ? (2 * s + tl) : 8;
        int tB = (s < 4) ? (2 * s + tl) : (8 + tl);
        short8 Bh[2], Bl[2];
#pragma unroll
        for (int nt = 0; nt < 2; nt++) {
            int u = ((nt * 16 + m) * 10 + tB) * 2 + half;
            Bh[nt] = *(const short8*)(w2h + (u << 3));
            Bl[nt] = *(const short8*)(w2l + (u << 3));
        }
        int ky = tA / 3, kx = tA - 3 * (tA / 3);
        short8 Ah[4], Al[4];
#pragma unroll
        for (int mt = 0; mt < 4; mt++) {
            int u = (((wid * 4 + mt + ky) * 2 + half) * 18) + m + kx;
            Ah[mt] = *(const short8*)(s_hi + (u << 3));
            Al[mt] = *(const short8*)(s_lo + (u << 3));
        }
#pragma unroll
        for (int mt = 0; mt < 4; mt++)
#pragma unroll
            for (int nt = 0; nt < 2; nt++) {
                float4v z = acc[mt][nt];
                z = __builtin_amdgcn_mfma_f32_16x16x32_bf16(Al[mt], Bh[nt], z, 0, 0, 0);
                z = __builtin_amdgcn_mfma_f32_16x16x32_bf16(Ah[mt], Bl[nt], z, 0, 0, 0);
                z = __builtin_amdgcn_mfma_f32_16x16x32_bf16(Ah[mt], Bh[nt], z, 0, 0, 0);
                acc[mt][nt] = z;
            }
    }

    // pool into LDS, stride 65 (conflict-free)
    float* s_pool = s_scratch;
    __syncthreads();
#pragma unroll
    for (int nt = 0; nt < 2; nt++) {
        int cout = nt * 16 + m;
        float bias = b2[cout];
#pragma unroll
        for (int mtp = 0; mtp < 2; mtp++) {
            float4v a0 = acc[2 * mtp][nt], a1 = acc[2 * mtp + 1][nt];
            float p0 = fmaxf(fmaxf(a0[0], a0[1]), fmaxf(a1[0], a1[1])) + bias;
            float p1 = fmaxf(fmaxf(a0[2], a0[3]), fmaxf(a1[2], a1[3])) + bias;
            int py = wid * 2 + mtp;
            int px = quad * 2;
            s_pool[cout * 65 + py * 8 + px]     = p0;
            s_pool[cout * 65 + py * 8 + px + 1] = p1;
        }
    }
    __syncthreads();

    // ---- VQ phase: each wave owns m-tile wid (positions 16*wid..+15) ----
    int pbase = wid * 16;
    short8 Ahi, Alo;
    float x2own = 0.0f;
#pragma unroll
    for (int j = 0; j < 8; j++) {
        float fe = s_pool[(quad * 8 + j) * 65 + pbase + m];
        x2own += fe * fe;
        unsigned short hi = f2bf(fe);
        Ahi[j] = (short)hi;
        Alo[j] = (short)f2bf(fe - bf2f(hi));
    }
    x2own += __shfl_xor(x2own, 16);
    x2own += __shfl_xor(x2own, 32);
    float x2r[4];
#pragma unroll
    for (int r = 0; r < 4; r++) x2r[r] = __shfl(x2own, quad * 4 + r);

    float best[4], best2[4];
    int bi[4];
#pragma unroll
    for (int r = 0; r < 4; r++) { best[r] = INFINITY; best2[r] = INFINITY; bi[r] = 0; }

    size_t boff = ((size_t)m << 5) + (quad << 3);
    short8 Bh = *(const short8*)(cbh + boff);
    short8 Bl = *(const short8*)(cbl + boff);
    float  c2v = c2g[m];

    for (int nt = 0; nt < 32; nt++) {
        short8 curBh = Bh, curBl = Bl;
        float  curc2 = c2v;
        if (nt < 31) {
            size_t o = boff + ((size_t)(nt + 1) << 9);
            Bh = *(const short8*)(cbh + o);
            Bl = *(const short8*)(cbl + o);
            c2v = c2g[(nt + 1) * 16 + m];
        }
        int ncode = nt * 16 + m;

        float4v z = {0.0f, 0.0f, 0.0f, 0.0f};
        z = __builtin_amdgcn_mfma_f32_16x16x32_bf16(Alo, curBh, z, 0, 0, 0);
        z = __builtin_amdgcn_mfma_f32_16x16x32_bf16(Ahi, curBl, z, 0, 0, 0);
        z = __builtin_amdgcn_mfma_f32_16x16x32_bf16(Ahi, curBh, z, 0, 0, 0);
#pragma unroll
        for (int r = 0; r < 4; r++) {
            float dist = fmaf(z[r], -2.0f, curc2);   // relative: true dist - x2
            best2[r] = fminf(best2[r], fmaxf(dist, best[r]));
            bool lt = dist < best[r];
            bi[r] = lt ? ncode : bi[r];
            best[r] = fminf(best[r], dist);
        }
    }

#pragma unroll
    for (int r = 0; r < 4; r++) {
        float b1v = best[r], b2v = best2[r];
        int   biv = bi[r];
#pragma unroll
        for (int mask = 1; mask < 16; mask <<= 1) {
            float ob = __shfl_xor(b1v, mask);
            float ob2 = __shfl_xor(b2v, mask);
            int   obi = __shfl_xor(biv, mask);
            b2v = fminf(fminf(b2v, ob2), fmaxf(b1v, ob));
            if (ob < b1v || (ob == b1v && obi < biv)) { b1v = ob; biv = obi; }
        }
        if (m == 0) {
            int p = pbase + quad * 4 + r;
            s_best[p] = b1v + x2r[r];
            s_best2[p] = b2v + x2r[r];
            s_bi[p] = biv;
        }
    }
    __syncthreads();

    // epilogue: wave 0, one thread per pooled position
    if (tid < 64) {
        float bb = s_best[tid], bb2 = s_best2[tid];
        int   kk = s_bi[tid];
        int py = tid >> 3, px = tid & 7;
        int sp = ((cy0 >> 1) + py) * 64 + (cx0 >> 1) + px;
        idx_out[(size_t)n * 4096 + sp] = (float)kk;

        // eps covers split-bf16 (~2e-3) + fast-erf (~1e-4) distance error
        float eps = 0.012f + 0.0003f * fabsf(bb);
        if (bb2 - bb < eps) {
            int slot = atomicAdd(nflag, 1);
            if (slot < MAXFLAG) flags[slot] = (n << 12) + sp;
        }

        float lsum = fmaxf(bb, 0.0f);
#pragma unroll
        for (int o = 32; o > 0; o >>= 1) lsum += __shfl_down(lsum, o);
        if (tid == 0) atomicAdd(loss_out, lsum * (1.0f / 8388608.0f));
    }
}

// LUT[code][pp][tap][cout] = sum_cin wc3[pp][cin][tap][cout] * cb[code][cin].
__global__ __launch_bounds__(256) void k_lut(const float* __restrict__ wc3,
                                             const float* __restrict__ cb,
                                             float* __restrict__ lut) {
    int code = blockIdx.x;
    int t = threadIdx.x;
    float s = 0.0f;
    if (code < 512) {
        int pp = t >> 6, rem = t & 63;
        const float* wp = wc3 + pp * 2048 + rem;
        const float* cr = cb + code * 32;
        for (int cin = 0; cin < 32; cin++)
            s += wp[cin * 64] * cr[cin];
    }
    lut[(size_t)code * 256 + t] = s;
}

// fp64 repair: exact erf, fixes idx_out only (unchanged).
__global__ __launch_bounds__(64) void k_repair(const float* __restrict__ x,
                                               const float* __restrict__ w1,
                                               const float* __restrict__ b1,
                                               const float* __restrict__ w2,
                                               const float* __restrict__ b2,
                                               const float* __restrict__ cb,
                                               float* __restrict__ idx_out,
                                               const int* __restrict__ nflag,
                                               const int* __restrict__ flags) {
    __shared__ double h1w[16][16];
    __shared__ double xvd[32];
    int lane = threadIdx.x;
    int cnt = *nflag;
    if (cnt > MAXFLAG) cnt = MAXFLAG;

    for (int fi = blockIdx.x; fi < cnt; fi += gridDim.x) {
        int pos = flags[fi];
        int n = pos >> 12, sp = pos & 4095, yo = sp >> 6, xo = sp & 63;

        int pix = lane >> 2, cg = lane & 3;
        int dy = pix >> 2, dx = pix & 3;
        int yh = 2 * yo - 1 + dy, xh = 2 * xo - 1 + dx;
        double hv[4] = {0.0, 0.0, 0.0, 0.0};
        if (yh >= 0 && yh < 128 && xh >= 0 && xh < 128) {
            const float* xin = x + (size_t)n * 65536;
            double patch[4][4];
            int y0 = 2 * yh - 1, x0 = 2 * xh - 1;
#pragma unroll
            for (int i = 0; i < 4; i++) {
                int iy = y0 + i;
                bool oy = (iy >= 0 && iy < 256);
#pragma unroll
                for (int j = 0; j < 4; j++) {
                    int ix = x0 + j;
                    patch[i][j] = (oy && ix >= 0 && ix < 256) ? (double)xin[iy * 256 + ix] : 0.0;
                }
            }
#pragma unroll
            for (int j = 0; j < 4; j++) {
                int c = cg * 4 + j;
                double mm = -INFINITY;
#pragma unroll
                for (int sy = 0; sy < 2; sy++)
#pragma unroll
                    for (int sx = 0; sx < 2; sx++) {
                        double acc = (double)b1[c];
#pragma unroll
                        for (int ky = 0; ky < 3; ky++)
#pragma unroll
                            for (int kx = 0; kx < 3; kx++)
                                acc += (double)w1[c * 9 + ky * 3 + kx] * patch[sy + ky][sx + kx];
                        mm = fmax(mm, acc);
                    }
                hv[j] = 0.5 * mm * (1.0 + erf(mm * 0.70710678118654752440));
            }
        }
        __syncthreads();
#pragma unroll
        for (int j = 0; j < 4; j++) h1w[cg * 4 + j][pix] = hv[j];
        __syncthreads();

        if (lane < 32) {
            double bb = (double)b2[lane];
            double acc[2][2] = {{bb, bb}, {bb, bb}};
            for (int cin = 0; cin < 16; cin++)
#pragma unroll
                for (int ky = 0; ky < 3; ky++)
#pragma unroll
                    for (int kx = 0; kx < 3; kx++) {
                        double wv = (double)w2[((lane * 16 + cin) * 3 + ky) * 3 + kx];
#pragma unroll
                        for (int sy = 0; sy < 2; sy++)
#pragma unroll
                            for (int sx = 0; sx < 2; sx++)
                                acc[sy][sx] += wv * h1w[cin][(sy + ky) * 4 + (sx + kx)];
                    }
            xvd[lane] = fmax(fmax(acc[0][0], acc[0][1]), fmax(acc[1][0], acc[1][1]));
        }
        __syncthreads();

        double x2 = 0.0;
        for (int d = 0; d < 32; d++) x2 += xvd[d] * xvd[d];
        double best = INFINITY;
        int bi = 0;
        for (int j = 0; j < 8; j++) {
            int k = lane * 8 + j;
            const float* cp = cb + k * 32;
            double c2 = 0.0, dot = 0.0;
#pragma unroll
            for (int d = 0; d < 32; d++) {
                double cd = (double)cp[d];
                c2 += cd * cd;
                dot += xvd[d] * cd;
            }
            double dist = x2 - 2.0 * dot + c2;
            if (dist < best) { best = dist; bi = k; }
        }
#pragma unroll
        for (int o = 32; o > 0; o >>= 1) {
            double od = __shfl_down(best, o);
            int oi = __shfl_down(bi, o);
            if (od < best || (od == best && oi < bi)) { best = od; bi = oi; }
        }
        bi = __shfl(bi, 0);

        if (lane == 0) idx_out[(size_t)n * 4096 + sp] = (float)bi;
    }
}

// prep: parity decoder weights + split-bf16 conv2 weights + split codebook.
__global__ __launch_bounds__(256) void k_prep(const float* __restrict__ w2,
                                              const float* __restrict__ w3,
                                              const float* __restrict__ w4,
                                              const float* __restrict__ cb,
                                              unsigned short* __restrict__ w2h,
                                              unsigned short* __restrict__ w2l,
                                              float* __restrict__ wc3,
                                              float* __restrict__ wc4,
                                              unsigned short* __restrict__ cbh,
                                              unsigned short* __restrict__ cbl,
                                              float* __restrict__ c2g) {
    const int masks[2][2] = {{1, 6}, {3, 4}};
    for (int e = threadIdx.x; e < 8192; e += 256) {
        int cout = e & 15, tap = (e >> 4) & 3, cin = (e >> 6) & 31, pp = e >> 11;
        int rm = masks[pp >> 1][tap >> 1], cm = masks[pp & 1][tap & 1];
        float s = 0.0f;
        for (int ky = 0; ky < 3; ky++)
            if ((rm >> ky) & 1)
                for (int kx = 0; kx < 3; kx++)
                    if ((cm >> kx) & 1) s += w3[(cout * 32 + cin) * 9 + ky * 3 + kx];
        wc3[e] = s;
    }
    for (int e = threadIdx.x; e < 1024; e += 256) {
        int tap = e & 3, cin = (e >> 2) & 15, pp = e >> 6;
        int rm = masks[pp >> 1][tap >> 1], cm = masks[pp & 1][tap & 1];
        float s = 0.0f;
        for (int ky = 0; ky < 3; ky++)
            if ((rm >> ky) & 1)
                for (int kx = 0; kx < 3; kx++)
                    if ((cm >> kx) & 1) s += w4[cin * 9 + ky * 3 + kx];
        wc4[e] = s;
    }
    for (int e = threadIdx.x; e < 5120; e += 256) {
        int cout = e / 160;
        int rem = e - cout * 160;
        int tap = rem >> 4;
        int cin = rem & 15;
        float v = 0.0f;
        if (tap < 9) {
            int ky = tap / 3, kx = tap - 3 * (tap / 3);
            v = w2[((cout * 16 + cin) * 3 + ky) * 3 + kx];
        }
        unsigned short hi = f2bf(v);
        unsigned short lo = f2bf(v - bf2f(hi));
        w2h[e] = hi;
        w2l[e] = lo;
    }
    for (int e = threadIdx.x; e < 16384; e += 256) {
        float v = cb[e];
        unsigned short hi = f2bf(v);
        cbh[e] = hi;
        cbl[e] = f2bf(v - bf2f(hi));
    }
    for (int k = threadIdx.x; k < 512; k += 256) {
        float c2 = 0.0f;
#pragma unroll
        for (int d = 0; d < 32; d++) {
            float fe = cb[k * 32 + d];
            c2 += fe * fe;
        }
        c2g[k] = c2;
    }
}

// Fused decoder (unchanged, exact erff): codes -> LUT adds + gelu -> conv4.
__global__ __launch_bounds__(256) void k_dec(const float* __restrict__ idxf,
                                             const float* __restrict__ lut,
                                             const float* __restrict__ b3,
                                             const float* __restrict__ wc4,
                                             const float* __restrict__ b4,
                                             float* __restrict__ out) {
    __shared__ int   s_code[11 * 11];
    __shared__ float s_h3[16 * 324];

    int tid = threadIdx.x;
    int n = blockIdx.x >> 6;
    int tile = blockIdx.x & 63;
    int ty = tile >> 3, tx = tile & 7;

    if (tid < 121) {
        int row = tid / 11, col = tid - row * 11;
        int ca = 8 * ty - 1 + row, cbx = 8 * tx - 1 + col;
        int code = 512;
        if (ca >= 0 && ca < 64 && cbx >= 0 && cbx < 64)
            code = (int)idxf[((size_t)n << 12) + (ca << 6) + cbx];
        s_code[tid] = code;
    }
    __syncthreads();

    for (int e = tid; e < 324; e += 256) {
        int r = e / 18, cc = e - r * 18;
        int Y = 16 * ty - 1 + r, X = 16 * tx - 1 + cc;
        float hv[16];
        if (Y >= 0 && Y < 128 && X >= 0 && X < 128) {
            int pp = ((Y & 1) << 1) | (X & 1);
            int la0 = (Y >> 1) - 1 + (Y & 1) - (8 * ty - 1);
            int lb0 = (X >> 1) - 1 + (X & 1) - (8 * tx - 1);
            float acc[16];
#pragma unroll
            for (int c = 0; c < 16; c++) acc[c] = b3[c];
#pragma unroll
            for (int dy = 0; dy < 2; dy++)
#pragma unroll
                for (int dx = 0; dx < 2; dx++) {
                    int code = s_code[(la0 + dy) * 11 + lb0 + dx];
                    const float4* lp = (const float4*)(lut + (size_t)code * 256 +
                                                       pp * 64 + (dy * 2 + dx) * 16);
#pragma unroll
                    for (int j = 0; j < 4; j++) {
                        float4 w = lp[j];
                        acc[4 * j + 0] += w.x;
                        acc[4 * j + 1] += w.y;
                        acc[4 * j + 2] += w.z;
                        acc[4 * j + 3] += w.w;
                    }
                }
#pragma unroll
            for (int c = 0; c < 16; c++) hv[c] = GELUF(acc[c]);
        } else {
#pragma unroll
            for (int c = 0; c < 16; c++) hv[c] = 0.0f;
        }
#pragma unroll
        for (int c = 0; c < 16; c++) s_h3[c * 324 + e] = hv[c];
    }
    __syncthreads();

    int ly = tid >> 4, lx = tid & 15;
    float bv = b4[0];
    float acc2[2][2] = {{bv, bv}, {bv, bv}};
    for (int cin = 0; cin < 16; cin++) {
        const float* hc = s_h3 + cin * 324;
        float v[3][3];
#pragma unroll
        for (int r = 0; r < 3; r++)
#pragma unroll
            for (int cc = 0; cc < 3; cc++)
                v[r][cc] = hc[(ly + r) * 18 + lx + cc];
#pragma unroll
        for (int py = 0; py < 2; py++)
#pragma unroll
            for (int px = 0; px < 2; px++)
#pragma unroll
                for (int dy = 0; dy < 2; dy++)
#pragma unroll
                    for (int dx = 0; dx < 2; dx++)
                        acc2[py][px] += wc4[(py * 2 + px) * 64 + cin * 4 + dy * 2 + dx] *
                                        v[py + dy][px + dx];
    }
    int a = 16 * ty + ly, b = 16 * tx + lx;
#pragma unroll
    for (int py = 0; py < 2; py++) {
        float2 f2 = make_float2(fminf(fmaxf(acc2[py][0], -1.0f), 1.0f),
                                fminf(fmaxf(acc2[py][1], -1.0f), 1.0f));
        *(float2*)(out + (size_t)n * 65536 + (2 * a + py) * 256 + 2 * b) = f2;
    }
}

extern "C" void kernel_launch(void* const* d_in, const int* in_sizes, int n_in,
                              void* d_out, int out_size, void* d_ws, size_t ws_size,
                              hipStream_t stream) {
    const float* x  = (const float*)d_in[0];
    const float* w1 = (const float*)d_in[1];
    const float* b1 = (const float*)d_in[2];
    const float* w2 = (const float*)d_in[3];
    const float* b2 = (const float*)d_in[4];
    const float* cb = (const float*)d_in[5];
    const float* w3 = (const float*)d_in[6];
    const float* b3 = (const float*)d_in[7];
    const float* w4 = (const float*)d_in[8];
    const float* b4 = (const float*)d_in[9];

    float* out      = (float*)d_out;
    float* idx_out  = out + 4194304;
    float* loss_out = out + 4194304 + 262144;

    char* ws = (char*)d_ws;
    float* lut = (float*)(ws + (size_t)67108864);   // 525 KB
    size_t T = 100663296;
    float* wc3 = (float*)(ws + T);
    float* wc4 = (float*)(ws + T + 32768);
    unsigned short* w2h = (unsigned short*)(ws + T + 36864);
    unsigned short* w2l = (unsigned short*)(ws + T + 47104);
    int* nflag = (int*)(ws + T + 57344);
    int* flags = (int*)(ws + T + 57408);            // 1 MB
    size_t T2 = T + 57408 + 1048576;
    unsigned short* cbh = (unsigned short*)(ws + T2);
    unsigned short* cbl = (unsigned short*)(ws + T2 + 32768);
    float* c2g = (float*)(ws + T2 + 65536);

    (void)hipMemsetAsync(loss_out, 0, 4, stream);
    (void)hipMemsetAsync(nflag, 0, 4, stream);

    k_prep<<<1, 256, 0, stream>>>(w2, w3, w4, cb, w2h, w2l, wc3, wc4, cbh, cbl, c2g);
    k_lut<<<513, 256, 0, stream>>>(wc3, cb, lut);
    k_enc<<<4096, 256, 0, stream>>>(x, w1, b1, w2h, w2l, b2, cbh, cbl, c2g,
                                    idx_out, loss_out, nflag, flags);
    k_repair<<<16384, 64, 0, stream>>>(x, w1, b1, w2, b2, cb, idx_out, nflag, flags);
    k_dec<<<4096, 256, 0, stream>>>(idx_out, lut, b3, wc4, b4, out);
}

// Round 19
// 359.248 us; speedup vs baseline: 1.4125x; 1.4125x over previous
//
#include <hip/hip_runtime.h>
#include <math.h>

// ---------------------------------------------------------------------------
// SimpleVQAutoEncoder forward.  (R17 configuration — best measured.)
// k_enc: FUSED conv1(+pool+gelu, split-bf16 in LDS, per-pixel work units)
//   + conv2 MFMA GEMM + pool (stride-65) + VQ (split-bf16 MFMA distances vs
//   L2-resident pre-split codebook) + near-tie flagging (eps 0.012+0.0003|b|)
//   + loss.
// fp64 repair fixes flagged indices => indices == numpy fp64 exactly.
// Decoder: k_dec (LUT[code][pp][tap][cout] adds -> gelu tile -> conv4).
// Outputs d_out (fp32): recon 4194304 | indices 262144 | loss 1
// ---------------------------------------------------------------------------

#define GELUF(v) (0.5f * (v) * (1.0f + erff((v) * 0.70710678118654752440f)))
#define MAXFLAG 262144

typedef __attribute__((ext_vector_type(8))) short short8;
typedef __attribute__((ext_vector_type(4))) float float4v;

static __device__ inline unsigned short f2bf(float f) {
    unsigned u = __float_as_uint(f);
    unsigned r = (u + 0x7FFFu + ((u >> 16) & 1u)) >> 16;
    return (unsigned short)r;
}
static __device__ inline float bf2f(unsigned short h) {
    return __uint_as_float(((unsigned)h) << 16);
}

// Fused encoder+VQ. Block = 16x16 conv2 positions (one 8x8 pooled tile).
__global__ __launch_bounds__(256) void k_enc(const float* __restrict__ x,
                                             const float* __restrict__ w1,
                                             const float* __restrict__ b1,
                                             const unsigned short* __restrict__ w2h,
                                             const unsigned short* __restrict__ w2l,
                                             const float* __restrict__ b2,
                                             const unsigned short* __restrict__ cbh,
                                             const unsigned short* __restrict__ cbl,
                                             const float* __restrict__ c2g,
                                             float* __restrict__ idx_out,
                                             float* __restrict__ loss_out,
                                             int* __restrict__ nflag,
                                             int* __restrict__ flags) {
    __shared__ __align__(16) float s_scratch[2112];  // x window 38x40 -> pool (stride 65)
    __shared__ __align__(16) unsigned short s_hi[18 * 2 * 18 * 8];
    __shared__ __align__(16) unsigned short s_lo[18 * 2 * 18 * 8];
    __shared__ float s_best[64], s_best2[64];
    __shared__ int   s_bi[64];

    int tid = threadIdx.x;
    int n = blockIdx.x >> 6;
    int tile = blockIdx.x & 63;
    int cx0 = (tile & 7) << 4, cy0 = (tile >> 3) << 4;

    // stage x window: 38x38, LDS stride 40, origin (2*cy0-3, 2*cx0-3)
    {
        const float* xin = x + (size_t)n * 65536;
        int gy0 = 2 * cy0 - 3, gx0 = 2 * cx0 - 3;
        for (int e = tid; e < 1444; e += 256) {
            int r = e / 38, c = e - r * 38;
            int gy = gy0 + r, gx = gx0 + c;
            float v = 0.0f;
            if (gy >= 0 && gy < 256 && gx >= 0 && gx < 256) v = xin[gy * 256 + gx];
            s_scratch[r * 40 + c] = v;
        }
    }
    __syncthreads();

    // conv1 phase: 18x18 halo pixels x 16ch, packed b128 writes.
    for (int e = tid; e < 324; e += 256) {
        int r = e / 18, c = e - r * 18;
        int hy = cy0 - 1 + r, hx = cx0 - 1 + c;
        uint ph[8], pl[8];
        if (hy >= 0 && hy < 128 && hx >= 0 && hx < 128) {
            float patch[4][4];
            const float* sp = s_scratch + (2 * r) * 40 + 2 * c;
#pragma unroll
            for (int i = 0; i < 4; i++)
#pragma unroll
                for (int j = 0; j < 4; j++)
                    patch[i][j] = sp[i * 40 + j];
            unsigned short hi[16], lo[16];
#pragma unroll
            for (int ch = 0; ch < 16; ch++) {
                float m = -INFINITY;
#pragma unroll
                for (int sy = 0; sy < 2; sy++)
#pragma unroll
                    for (int sx = 0; sx < 2; sx++) {
                        float acc = b1[ch];
#pragma unroll
                        for (int ky = 0; ky < 3; ky++)
#pragma unroll
                            for (int kx = 0; kx < 3; kx++)
                                acc += w1[ch * 9 + ky * 3 + kx] * patch[sy + ky][sx + kx];
                        m = fmaxf(m, acc);
                    }
                float g = GELUF(m);
                hi[ch] = f2bf(g);
                lo[ch] = f2bf(g - bf2f(hi[ch]));
            }
#pragma unroll
            for (int dw = 0; dw < 8; dw++) {
                ph[dw] = (uint)hi[2 * dw] | ((uint)hi[2 * dw + 1] << 16);
                pl[dw] = (uint)lo[2 * dw] | ((uint)lo[2 * dw + 1] << 16);
            }
        } else {
#pragma unroll
            for (int dw = 0; dw < 8; dw++) { ph[dw] = 0; pl[dw] = 0; }
        }
        ((uint4*)s_hi)[(r * 2) * 18 + c]     = make_uint4(ph[0], ph[1], ph[2], ph[3]);
        ((uint4*)s_hi)[(r * 2 + 1) * 18 + c] = make_uint4(ph[4], ph[5], ph[6], ph[7]);
        ((uint4*)s_lo)[(r * 2) * 18 + c]     = make_uint4(pl[0], pl[1], pl[2], pl[3]);
        ((uint4*)s_lo)[(r * 2 + 1) * 18 + c] = make_uint4(pl[4], pl[5], pl[6], pl[7]);
    }
    __syncthreads();

    // conv2 MFMA phase; B-frags from global (L2-hot w2h/w2l).
    int lane = tid & 63, wid = tid >> 6;
    int m = lane & 15, quad = lane >> 4;
    int tl = quad >> 1, half = quad & 1;

    float4v acc[4][2];
#pragma unroll
    for (int mt = 0; mt < 4; mt++)
#pragma unroll
        for (int nt = 0; nt < 2; nt++)
            acc[mt][nt] = (float4v){0.0f, 0.0f, 0.0f, 0.0f};

    for (int s = 0; s < 5; s++) {
        int tA = (s < 4) ? (2 * s + tl) : 8;
        int tB = (s < 4) ? (2 * s + tl) : (8 + tl);
        short8 Bh[2], Bl[2];
#pragma unroll
        for (int nt = 0; nt < 2; nt++) {
            int u = ((nt * 16 + m) * 10 + tB) * 2 + half;
            Bh[nt] = *(const short8*)(w2h + (u << 3));
            Bl[nt] = *(const short8*)(w2l + (u << 3));
        }
        int ky = tA / 3, kx = tA - 3 * (tA / 3);
        short8 Ah[4], Al[4];
#pragma unroll
        for (int mt = 0; mt < 4; mt++) {
            int u = (((wid * 4 + mt + ky) * 2 + half) * 18) + m + kx;
            Ah[mt] = *(const short8*)(s_hi + (u << 3));
            Al[mt] = *(const short8*)(s_lo + (u << 3));
        }
#pragma unroll
        for (int mt = 0; mt < 4; mt++)
#pragma unroll
            for (int nt = 0; nt < 2; nt++) {
                float4v z = acc[mt][nt];
                z = __builtin_amdgcn_mfma_f32_16x16x32_bf16(Al[mt], Bh[nt], z, 0, 0, 0);
                z = __builtin_amdgcn_mfma_f32_16x16x32_bf16(Ah[mt], Bl[nt], z, 0, 0, 0);
                z = __builtin_amdgcn_mfma_f32_16x16x32_bf16(Ah[mt], Bh[nt], z, 0, 0, 0);
                acc[mt][nt] = z;
            }
    }

    // pool into LDS, stride 65 (conflict-free)
    float* s_pool = s_scratch;
    __syncthreads();
#pragma unroll
    for (int nt = 0; nt < 2; nt++) {
        int cout = nt * 16 + m;
        float bias = b2[cout];
#pragma unroll
        for (int mtp = 0; mtp < 2; mtp++) {
            float4v a0 = acc[2 * mtp][nt], a1 = acc[2 * mtp + 1][nt];
            float p0 = fmaxf(fmaxf(a0[0], a0[1]), fmaxf(a1[0], a1[1])) + bias;
            float p1 = fmaxf(fmaxf(a0[2], a0[3]), fmaxf(a1[2], a1[3])) + bias;
            int py = wid * 2 + mtp;
            int px = quad * 2;
            s_pool[cout * 65 + py * 8 + px]     = p0;
            s_pool[cout * 65 + py * 8 + px + 1] = p1;
        }
    }
    __syncthreads();

    // ---- VQ phase: each wave owns m-tile wid (positions 16*wid..+15) ----
    int pbase = wid * 16;
    short8 Ahi, Alo;
    float x2own = 0.0f;
#pragma unroll
    for (int j = 0; j < 8; j++) {
        float fe = s_pool[(quad * 8 + j) * 65 + pbase + m];
        x2own += fe * fe;
        unsigned short hi = f2bf(fe);
        Ahi[j] = (short)hi;
        Alo[j] = (short)f2bf(fe - bf2f(hi));
    }
    x2own += __shfl_xor(x2own, 16);
    x2own += __shfl_xor(x2own, 32);
    float x2r[4];
#pragma unroll
    for (int r = 0; r < 4; r++) x2r[r] = __shfl(x2own, quad * 4 + r);

    float best[4], best2[4];
    int bi[4];
#pragma unroll
    for (int r = 0; r < 4; r++) { best[r] = INFINITY; best2[r] = INFINITY; bi[r] = 0; }

    size_t boff = ((size_t)m << 5) + (quad << 3);
    short8 Bh = *(const short8*)(cbh + boff);
    short8 Bl = *(const short8*)(cbl + boff);
    float  c2v = c2g[m];

    for (int nt = 0; nt < 32; nt++) {
        short8 curBh = Bh, curBl = Bl;
        float  curc2 = c2v;
        if (nt < 31) {
            size_t o = boff + ((size_t)(nt + 1) << 9);
            Bh = *(const short8*)(cbh + o);
            Bl = *(const short8*)(cbl + o);
            c2v = c2g[(nt + 1) * 16 + m];
        }
        int ncode = nt * 16 + m;

        float4v z = {0.0f, 0.0f, 0.0f, 0.0f};
        z = __builtin_amdgcn_mfma_f32_16x16x32_bf16(Alo, curBh, z, 0, 0, 0);
        z = __builtin_amdgcn_mfma_f32_16x16x32_bf16(Ahi, curBl, z, 0, 0, 0);
        z = __builtin_amdgcn_mfma_f32_16x16x32_bf16(Ahi, curBh, z, 0, 0, 0);
#pragma unroll
        for (int r = 0; r < 4; r++) {
            float dist = fmaf(z[r], -2.0f, curc2);   // relative: true dist - x2
            best2[r] = fminf(best2[r], fmaxf(dist, best[r]));
            bool lt = dist < best[r];
            bi[r] = lt ? ncode : bi[r];
            best[r] = fminf(best[r], dist);
        }
    }

#pragma unroll
    for (int r = 0; r < 4; r++) {
        float b1v = best[r], b2v = best2[r];
        int   biv = bi[r];
#pragma unroll
        for (int mask = 1; mask < 16; mask <<= 1) {
            float ob = __shfl_xor(b1v, mask);
            float ob2 = __shfl_xor(b2v, mask);
            int   obi = __shfl_xor(biv, mask);
            b2v = fminf(fminf(b2v, ob2), fmaxf(b1v, ob));
            if (ob < b1v || (ob == b1v && obi < biv)) { b1v = ob; biv = obi; }
        }
        if (m == 0) {
            int p = pbase + quad * 4 + r;
            s_best[p] = b1v + x2r[r];
            s_best2[p] = b2v + x2r[r];
            s_bi[p] = biv;
        }
    }
    __syncthreads();

    // epilogue: wave 0, one thread per pooled position
    if (tid < 64) {
        float bb = s_best[tid], bb2 = s_best2[tid];
        int   kk = s_bi[tid];
        int py = tid >> 3, px = tid & 7;
        int sp = ((cy0 >> 1) + py) * 64 + (cx0 >> 1) + px;
        idx_out[(size_t)n * 4096 + sp] = (float)kk;

        // eps >= 6x analytic worst-case split-bf16 gap error (validated R16)
        float eps = 0.012f + 0.0003f * fabsf(bb);
        if (bb2 - bb < eps) {
            int slot = atomicAdd(nflag, 1);
            if (slot < MAXFLAG) flags[slot] = (n << 12) + sp;
        }

        float lsum = fmaxf(bb, 0.0f);
#pragma unroll
        for (int o = 32; o > 0; o >>= 1) lsum += __shfl_down(lsum, o);
        if (tid == 0) atomicAdd(loss_out, lsum * (1.0f / 8388608.0f));
    }
}

// LUT[code][pp][tap][cout] = sum_cin wc3[pp][cin][tap][cout] * cb[code][cin].
__global__ __launch_bounds__(256) void k_lut(const float* __restrict__ wc3,
                                             const float* __restrict__ cb,
                                             float* __restrict__ lut) {
    int code = blockIdx.x;
    int t = threadIdx.x;
    float s = 0.0f;
    if (code < 512) {
        int pp = t >> 6, rem = t & 63;
        const float* wp = wc3 + pp * 2048 + rem;
        const float* cr = cb + code * 32;
        for (int cin = 0; cin < 32; cin++)
            s += wp[cin * 64] * cr[cin];
    }
    lut[(size_t)code * 256 + t] = s;
}

// fp64 repair: fixes idx_out only (unchanged).
__global__ __launch_bounds__(64) void k_repair(const float* __restrict__ x,
                                               const float* __restrict__ w1,
                                               const float* __restrict__ b1,
                                               const float* __restrict__ w2,
                                               const float* __restrict__ b2,
                                               const float* __restrict__ cb,
                                               float* __restrict__ idx_out,
                                               const int* __restrict__ nflag,
                                               const int* __restrict__ flags) {
    __shared__ double h1w[16][16];
    __shared__ double xvd[32];
    int lane = threadIdx.x;
    int cnt = *nflag;
    if (cnt > MAXFLAG) cnt = MAXFLAG;

    for (int fi = blockIdx.x; fi < cnt; fi += gridDim.x) {
        int pos = flags[fi];
        int n = pos >> 12, sp = pos & 4095, yo = sp >> 6, xo = sp & 63;

        int pix = lane >> 2, cg = lane & 3;
        int dy = pix >> 2, dx = pix & 3;
        int yh = 2 * yo - 1 + dy, xh = 2 * xo - 1 + dx;
        double hv[4] = {0.0, 0.0, 0.0, 0.0};
        if (yh >= 0 && yh < 128 && xh >= 0 && xh < 128) {
            const float* xin = x + (size_t)n * 65536;
            double patch[4][4];
            int y0 = 2 * yh - 1, x0 = 2 * xh - 1;
#pragma unroll
            for (int i = 0; i < 4; i++) {
                int iy = y0 + i;
                bool oy = (iy >= 0 && iy < 256);
#pragma unroll
                for (int j = 0; j < 4; j++) {
                    int ix = x0 + j;
                    patch[i][j] = (oy && ix >= 0 && ix < 256) ? (double)xin[iy * 256 + ix] : 0.0;
                }
            }
#pragma unroll
            for (int j = 0; j < 4; j++) {
                int c = cg * 4 + j;
                double mm = -INFINITY;
#pragma unroll
                for (int sy = 0; sy < 2; sy++)
#pragma unroll
                    for (int sx = 0; sx < 2; sx++) {
                        double acc = (double)b1[c];
#pragma unroll
                        for (int ky = 0; ky < 3; ky++)
#pragma unroll
                            for (int kx = 0; kx < 3; kx++)
                                acc += (double)w1[c * 9 + ky * 3 + kx] * patch[sy + ky][sx + kx];
                        mm = fmax(mm, acc);
                    }
                hv[j] = 0.5 * mm * (1.0 + erf(mm * 0.70710678118654752440));
            }
        }
        __syncthreads();
#pragma unroll
        for (int j = 0; j < 4; j++) h1w[cg * 4 + j][pix] = hv[j];
        __syncthreads();

        if (lane < 32) {
            double bb = (double)b2[lane];
            double acc[2][2] = {{bb, bb}, {bb, bb}};
            for (int cin = 0; cin < 16; cin++)
#pragma unroll
                for (int ky = 0; ky < 3; ky++)
#pragma unroll
                    for (int kx = 0; kx < 3; kx++) {
                        double wv = (double)w2[((lane * 16 + cin) * 3 + ky) * 3 + kx];
#pragma unroll
                        for (int sy = 0; sy < 2; sy++)
#pragma unroll
                            for (int sx = 0; sx < 2; sx++)
                                acc[sy][sx] += wv * h1w[cin][(sy + ky) * 4 + (sx + kx)];
                    }
            xvd[lane] = fmax(fmax(acc[0][0], acc[0][1]), fmax(acc[1][0], acc[1][1]));
        }
        __syncthreads();

        double x2 = 0.0;
        for (int d = 0; d < 32; d++) x2 += xvd[d] * xvd[d];
        double best = INFINITY;
        int bi = 0;
        for (int j = 0; j < 8; j++) {
            int k = lane * 8 + j;
            const float* cp = cb + k * 32;
            double c2 = 0.0, dot = 0.0;
#pragma unroll
            for (int d = 0; d < 32; d++) {
                double cd = (double)cp[d];
                c2 += cd * cd;
                dot += xvd[d] * cd;
            }
            double dist = x2 - 2.0 * dot + c2;
            if (dist < best) { best = dist; bi = k; }
        }
#pragma unroll
        for (int o = 32; o > 0; o >>= 1) {
            double od = __shfl_down(best, o);
            int oi = __shfl_down(bi, o);
            if (od < best || (od == best && oi < bi)) { best = od; bi = oi; }
        }
        bi = __shfl(bi, 0);

        if (lane == 0) idx_out[(size_t)n * 4096 + sp] = (float)bi;
    }
}

// prep: parity decoder weights + split-bf16 conv2 weights + split codebook.
__global__ __launch_bounds__(256) void k_prep(const float* __restrict__ w2,
                                              const float* __restrict__ w3,
                                              const float* __restrict__ w4,
                                              const float* __restrict__ cb,
                                              unsigned short* __restrict__ w2h,
                                              unsigned short* __restrict__ w2l,
                                              float* __restrict__ wc3,
                                              float* __restrict__ wc4,
                                              unsigned short* __restrict__ cbh,
                                              unsigned short* __restrict__ cbl,
                                              float* __restrict__ c2g) {
    const int masks[2][2] = {{1, 6}, {3, 4}};
    for (int e = threadIdx.x; e < 8192; e += 256) {
        int cout = e & 15, tap = (e >> 4) & 3, cin = (e >> 6) & 31, pp = e >> 11;
        int rm = masks[pp >> 1][tap >> 1], cm = masks[pp & 1][tap & 1];
        float s = 0.0f;
        for (int ky = 0; ky < 3; ky++)
            if ((rm >> ky) & 1)
                for (int kx = 0; kx < 3; kx++)
                    if ((cm >> kx) & 1) s += w3[(cout * 32 + cin) * 9 + ky * 3 + kx];
        wc3[e] = s;
    }
    for (int e = threadIdx.x; e < 1024; e += 256) {
        int tap = e & 3, cin = (e >> 2) & 15, pp = e >> 6;
        int rm = masks[pp >> 1][tap >> 1], cm = masks[pp & 1][tap & 1];
        float s = 0.0f;
        for (int ky = 0; ky < 3; ky++)
            if ((rm >> ky) & 1)
                for (int kx = 0; kx < 3; kx++)
                    if ((cm >> kx) & 1) s += w4[cin * 9 + ky * 3 + kx];
        wc4[e] = s;
    }
    for (int e = threadIdx.x; e < 5120; e += 256) {
        int cout = e / 160;
        int rem = e - cout * 160;
        int tap = rem >> 4;
        int cin = rem & 15;
        float v = 0.0f;
        if (tap < 9) {
            int ky = tap / 3, kx = tap - 3 * (tap / 3);
            v = w2[((cout * 16 + cin) * 3 + ky) * 3 + kx];
        }
        unsigned short hi = f2bf(v);
        unsigned short lo = f2bf(v - bf2f(hi));
        w2h[e] = hi;
        w2l[e] = lo;
    }
    for (int e = threadIdx.x; e < 16384; e += 256) {
        float v = cb[e];
        unsigned short hi = f2bf(v);
        cbh[e] = hi;
        cbl[e] = f2bf(v - bf2f(hi));
    }
    for (int k = threadIdx.x; k < 512; k += 256) {
        float c2 = 0.0f;
#pragma unroll
        for (int d = 0; d < 32; d++) {
            float fe = cb[k * 32 + d];
            c2 += fe * fe;
        }
        c2g[k] = c2;
    }
}

// Fused decoder (unchanged): codes -> LUT adds + gelu -> conv4 -> clip.
__global__ __launch_bounds__(256) void k_dec(const float* __restrict__ idxf,
                                             const float* __restrict__ lut,
                                             const float* __restrict__ b3,
                                             const float* __restrict__ wc4,
                                             const float* __restrict__ b4,
                                             float* __restrict__ out) {
    __shared__ int   s_code[11 * 11];
    __shared__ float s_h3[16 * 324];

    int tid = threadIdx.x;
    int n = blockIdx.x >> 6;
    int tile = blockIdx.x & 63;
    int ty = tile >> 3, tx = tile & 7;

    if (tid < 121) {
        int row = tid / 11, col = tid - row * 11;
        int ca = 8 * ty - 1 + row, cbx = 8 * tx - 1 + col;
        int code = 512;
        if (ca >= 0 && ca < 64 && cbx >= 0 && cbx < 64)
            code = (int)idxf[((size_t)n << 12) + (ca << 6) + cbx];
        s_code[tid] = code;
    }
    __syncthreads();

    for (int e = tid; e < 324; e += 256) {
        int r = e / 18, cc = e - r * 18;
        int Y = 16 * ty - 1 + r, X = 16 * tx - 1 + cc;
        float hv[16];
        if (Y >= 0 && Y < 128 && X >= 0 && X < 128) {
            int pp = ((Y & 1) << 1) | (X & 1);
            int la0 = (Y >> 1) - 1 + (Y & 1) - (8 * ty - 1);
            int lb0 = (X >> 1) - 1 + (X & 1) - (8 * tx - 1);
            float acc[16];
#pragma unroll
            for (int c = 0; c < 16; c++) acc[c] = b3[c];
#pragma unroll
            for (int dy = 0; dy < 2; dy++)
#pragma unroll
                for (int dx = 0; dx < 2; dx++) {
                    int code = s_code[(la0 + dy) * 11 + lb0 + dx];
                    const float4* lp = (const float4*)(lut + (size_t)code * 256 +
                                                       pp * 64 + (dy * 2 + dx) * 16);
#pragma unroll
                    for (int j = 0; j < 4; j++) {
                        float4 w = lp[j];
                        acc[4 * j + 0] += w.x;
                        acc[4 * j + 1] += w.y;
                        acc[4 * j + 2] += w.z;
                        acc[4 * j + 3] += w.w;
                    }
                }
#pragma unroll
            for (int c = 0; c < 16; c++) hv[c] = GELUF(acc[c]);
        } else {
#pragma unroll
            for (int c = 0; c < 16; c++) hv[c] = 0.0f;
        }
#pragma unroll
        for (int c = 0; c < 16; c++) s_h3[c * 324 + e] = hv[c];
    }
    __syncthreads();

    int ly = tid >> 4, lx = tid & 15;
    float bv = b4[0];
    float acc2[2][2] = {{bv, bv}, {bv, bv}};
    for (int cin = 0; cin < 16; cin++) {
        const float* hc = s_h3 + cin * 324;
        float v[3][3];
#pragma unroll
        for (int r = 0; r < 3; r++)
#pragma unroll
            for (int cc = 0; cc < 3; cc++)
                v[r][cc] = hc[(ly + r) * 18 + lx + cc];
#pragma unroll
        for (int py = 0; py < 2; py++)
#pragma unroll
            for (int px = 0; px < 2; px++)
#pragma unroll
                for (int dy = 0; dy < 2; dy++)
#pragma unroll
                    for (int dx = 0; dx < 2; dx++)
                        acc2[py][px] += wc4[(py * 2 + px) * 64 + cin * 4 + dy * 2 + dx] *
                                        v[py + dy][px + dx];
    }
    int a = 16 * ty + ly, b = 16 * tx + lx;
#pragma unroll
    for (int py = 0; py < 2; py++) {
        float2 f2 = make_float2(fminf(fmaxf(acc2[py][0], -1.0f), 1.0f),
                                fminf(fmaxf(acc2[py][1], -1.0f), 1.0f));
        *(float2*)(out + (size_t)n * 65536 + (2 * a + py) * 256 + 2 * b) = f2;
    }
}

extern "C" void kernel_launch(void* const* d_in, const int* in_sizes, int n_in,
                              void* d_out, int out_size, void* d_ws, size_t ws_size,
                              hipStream_t stream) {
    const float* x  = (const float*)d_in[0];
    const float* w1 = (const float*)d_in[1];
    const float* b1 = (const float*)d_in[2];
    const float* w2 = (const float*)d_in[3];
    const float* b2 = (const float*)d_in[4];
    const float* cb = (const float*)d_in[5];
    const float* w3 = (const float*)d_in[6];
    const float* b3 = (const float*)d_in[7];
    const float* w4 = (const float*)d_in[8];
    const float* b4 = (const float*)d_in[9];

    float* out      = (float*)d_out;
    float* idx_out  = out + 4194304;
    float* loss_out = out + 4194304 + 262144;

    char* ws = (char*)d_ws;
    float* lut = (float*)(ws + (size_t)67108864);   // 525 KB
    size_t T = 100663296;
    float* wc3 = (float*)(ws + T);
    float* wc4 = (float*)(ws + T + 32768);
    unsigned short* w2h = (unsigned short*)(ws + T + 36864);
    unsigned short* w2l = (unsigned short*)(ws + T + 47104);
    int* nflag = (int*)(ws + T + 57344);
    int* flags = (int*)(ws + T + 57408);            // 1 MB
    size_t T2 = T + 57408 + 1048576;
    unsigned short* cbh = (unsigned short*)(ws + T2);
    unsigned short* cbl = (unsigned short*)(ws + T2 + 32768);
    float* c2g = (float*)(ws + T2 + 65536);

    (void)hipMemsetAsync(loss_out, 0, 4, stream);
    (void)hipMemsetAsync(nflag, 0, 4, stream);

    k_prep<<<1, 256, 0, stream>>>(w2, w3, w4, cb, w2h, w2l, wc3, wc4, cbh, cbl, c2g);
    k_lut<<<513, 256, 0, stream>>>(wc3, cb, lut);
    k_enc<<<4096, 256, 0, stream>>>(x, w1, b1, w2h, w2l, b2, cbh, cbl, c2g,
                                    idx_out, loss_out, nflag, flags);
    k_repair<<<16384, 64, 0, stream>>>(x, w1, b1, w2, b2, cb, idx_out, nflag, flags);
    k_dec<<<4096, 256, 0, stream>>>(idx_out, lut, b3, wc4, b4, out);
}